// Round 1
// baseline (524.060 us; speedup 1.0000x reference)
//
#include <hip/hip_runtime.h>

// ---- types for MFMA (gfx950: __builtin_amdgcn_mfma_f32_16x16x32_bf16 takes V8bf16) ----
using bf16_t = __bf16;
using bf16x4 = __bf16 __attribute__((ext_vector_type(4)));
using bf16x8 = __bf16 __attribute__((ext_vector_type(8)));
using f32x4  = float  __attribute__((ext_vector_type(4)));

#define MFMA16(a, b, c) __builtin_amdgcn_mfma_f32_16x16x32_bf16((a), (b), (c), 0, 0, 0)

// Problem constants
// B=4096 windows, N=49 tokens, C=192, H=6, d=32, nW=64, 3C=576
// MFMA fragment conventions (verified on gfx950, learn_hip m89/m91/m120):
//   A-frag : lane(g=lane>>4, m=lane&15) holds A[m][g*8+j], j=0..7 (contiguous k)
//   B-frag : lane(g, n=lane&15)        holds B[g*8+j][n]          (contiguous k)
//   C/D    : lane(g, c=lane&15)        holds D[4*g+r][c], r=0..3

// ---------------------------------------------------------------------------
// Prep: swizzle weights into fragment order (bf16) in workspace.
//  wA  [mt(36)][ks(6)][lane(64)][8] : A-frag of w_qkv^T  (w_qkv^T[ch3][cc])
//  w2B [ks(6)][nt(12)][lane(64)][8] : B-frag of w_proj   (w_proj[cc][ch2])
// ---------------------------------------------------------------------------
__global__ void prep_weights(const float* __restrict__ wqkv,
                             const float* __restrict__ wproj,
                             bf16_t* __restrict__ wA,
                             bf16_t* __restrict__ w2B) {
    int idx = blockIdx.x * 256 + threadIdx.x;
    const int N1 = 36 * 6 * 64 * 8;  // 110592
    if (idx < N1) {
        int j = idx & 7, L = (idx >> 3) & 63, q = idx >> 9;
        int ks = q % 6, mt = q / 6;
        int cc = ks * 32 + (L >> 4) * 8 + j;   // k index (0..191)
        int ch = mt * 16 + (L & 15);           // ch3 (0..575)
        wA[idx] = (bf16_t)wqkv[cc * 576 + ch];
    } else {
        int idx2 = idx - N1;
        if (idx2 < 6 * 12 * 64 * 8) {          // 36864
            int j = idx2 & 7, L = (idx2 >> 3) & 63, q = idx2 >> 9;
            int nt = q % 12, ks = q / 12;
            int cc = ks * 32 + (L >> 4) * 8 + j;  // k index (0..191)
            int ch = nt * 16 + (L & 15);          // ch2 (0..191)
            w2B[idx2] = (bf16_t)wproj[cc * 192 + ch];
        }
    }
}

// ---------------------------------------------------------------------------
// Fused window attention: one block per window (4096 blocks x 384 threads).
// ---------------------------------------------------------------------------
__global__ __launch_bounds__(384, 2) void fused_window_attn(
    const float* __restrict__ x,     // [4096][49][192]
    const float* __restrict__ mask,  // [64][1][49][49]
    const bf16_t* __restrict__ wA,   // swizzled qkv weights
    const bf16_t* __restrict__ w2B,  // swizzled proj weights
    const float* __restrict__ bias,  // [192]
    float* __restrict__ out)         // [4096][49][192]
{
    constexpr int QP  = 40;   // q/k pitch (bf16): 32 + 8 pad, row stride 80B (16B mult)
    constexpr int VP  = 72;   // v^T pitch: 64 + 8, row stride 144B
    constexpr int PMP = 72;   // premask pitch
    constexpr int PP  = 72;   // P pitch
    constexpr int AOP = 200;  // attn_out pitch: 192 + 8

    __shared__ __align__(16) char smem[153600];
    bf16_t* qS  = (bf16_t*)smem;        // [6][64][QP]  = 15360 elems
    bf16_t* kS  = qS  + 6 * 64 * QP;    // 15360
    bf16_t* vS  = kS  + 6 * 64 * QP;    // [6][32][VP]  = 13824
    bf16_t* pmS = vS  + 6 * 32 * VP;    // [64][PMP]    = 4608
    bf16_t* pS  = pmS + 64 * PMP;       // [6][64][PP]  = 27648
    bf16_t* aoS = (bf16_t*)smem;        // alias qS: [64][AOP] = 12800 elems

    const int b    = blockIdx.x;
    const int tid  = threadIdx.x;
    const int wid  = tid >> 6;   // wave 0..5
    const int lane = tid & 63;
    const int g    = lane >> 4;  // quad 0..3
    const int c    = lane & 15;

    // ---- stage premask[i][t]: mask + (-1e30 kills padded t>=49 columns) ----
    const float* mw = mask + (size_t)(b & 63) * (49 * 49);
    for (int idx = tid; idx < 64 * 64; idx += 384) {
        int i = idx >> 6, t = idx & 63;
        float v;
        if (t < 49) v = (i < 49) ? mw[i * 49 + t] : 0.0f;
        else        v = -1e30f;
        pmS[i * PMP + t] = (bf16_t)v;
    }

    // =========== Phase A: qkv^T = w_qkv^T (A) * x^T (B) ===========
    // M = ch3 (576, wave w owns mtiles w*6..w*6+5), N = tok (64), K = 192
    const float* xb = x + (size_t)b * (49 * 192);
    f32x4 acc[6][4];
#pragma unroll
    for (int m = 0; m < 6; ++m)
#pragma unroll
        for (int n = 0; n < 4; ++n) acc[m][n] = (f32x4){0.f, 0.f, 0.f, 0.f};

#pragma unroll
    for (int ks = 0; ks < 6; ++ks) {
        // B-frags from global x (fp32 -> bf16), zero-pad tokens >= 49
        bf16x8 Bf[4];
#pragma unroll
        for (int nt = 0; nt < 4; ++nt) {
            int tok = nt * 16 + c;
            f32x4 lo = (f32x4){0.f, 0.f, 0.f, 0.f};
            f32x4 hi = (f32x4){0.f, 0.f, 0.f, 0.f};
            if (tok < 49) {
                const f32x4* p = (const f32x4*)(xb + tok * 192 + ks * 32 + g * 8);
                lo = p[0]; hi = p[1];
            }
            bf16x8 t;
            t[0] = (bf16_t)lo[0]; t[1] = (bf16_t)lo[1];
            t[2] = (bf16_t)lo[2]; t[3] = (bf16_t)lo[3];
            t[4] = (bf16_t)hi[0]; t[5] = (bf16_t)hi[1];
            t[6] = (bf16_t)hi[2]; t[7] = (bf16_t)hi[3];
            Bf[nt] = t;
        }
#pragma unroll
        for (int ml = 0; ml < 6; ++ml) {
            int mt = wid * 6 + ml;
            bf16x8 Af = *(const bf16x8*)(wA + (((size_t)mt * 6 + ks) * 64 + lane) * 8);
#pragma unroll
            for (int nt = 0; nt < 4; ++nt)
                acc[ml][nt] = MFMA16(Af, Bf[nt], acc[ml][nt]);
        }
    }

    // ---- route stores: q,k -> [h][tok][d] row-major (b64); v -> [h][d][tok] ----
    const int typ = wid >> 1;  // 0=q (waves 0,1), 1=k, 2=v  (wave-uniform)
#pragma unroll
    for (int ml = 0; ml < 6; ++ml) {
        int ch0 = (wid * 6 + ml) * 16 + g * 4;  // ch3 of r=0
        int rel = ch0 - typ * 192;              // 0..191 within q/k/v
        int hh  = rel >> 5;
        int dd0 = rel & 31;
#pragma unroll
        for (int nt = 0; nt < 4; ++nt) {
            int tok = nt * 16 + c;
            f32x4 a = acc[ml][nt];
            if (typ == 0) {
                bf16x4 v4 = {(bf16_t)a[0], (bf16_t)a[1], (bf16_t)a[2], (bf16_t)a[3]};
                *(bf16x4*)(qS + hh * (64 * QP) + tok * QP + dd0) = v4;
            } else if (typ == 1) {
                bf16x4 v4 = {(bf16_t)a[0], (bf16_t)a[1], (bf16_t)a[2], (bf16_t)a[3]};
                *(bf16x4*)(kS + hh * (64 * QP) + tok * QP + dd0) = v4;
            } else {
                bf16_t* vb = vS + hh * (32 * VP) + tok;
                vb[(dd0 + 0) * VP] = (bf16_t)a[0];
                vb[(dd0 + 1) * VP] = (bf16_t)a[1];
                vb[(dd0 + 2) * VP] = (bf16_t)a[2];
                vb[(dd0 + 3) * VP] = (bf16_t)a[3];
            }
        }
    }
    __syncthreads();  // qkv + premask ready

    // =========== Phase B: attention, wave = head ===========
    const bf16_t* qh = qS + wid * (64 * QP);
    const bf16_t* kh = kS + wid * (64 * QP);
    const bf16_t* vh = vS + wid * (32 * VP);
    bf16_t*       Ph = pS + wid * (64 * PP);

    // S^T[t][i] = sum_d k[t][d] * q[i][d]   (A = k, B = q, K = 32 -> 1 kstep)
    f32x4 sacc[4][4];
#pragma unroll
    for (int mt = 0; mt < 4; ++mt)
#pragma unroll
        for (int nt = 0; nt < 4; ++nt) sacc[mt][nt] = (f32x4){0.f, 0.f, 0.f, 0.f};

    bf16x8 Ak[4], Bq[4];
#pragma unroll
    for (int mt = 0; mt < 4; ++mt)
        Ak[mt] = *(const bf16x8*)(kh + (mt * 16 + c) * QP + g * 8);
#pragma unroll
    for (int nt = 0; nt < 4; ++nt)
        Bq[nt] = *(const bf16x8*)(qh + (nt * 16 + c) * QP + g * 8);
#pragma unroll
    for (int mt = 0; mt < 4; ++mt)
#pragma unroll
        for (int nt = 0; nt < 4; ++nt)
            sacc[mt][nt] = MFMA16(Ak[mt], Bq[nt], sacc[mt][nt]);

    // softmax over t (rows of S^T): in-lane 16 values + shfl_xor over g-lanes
    const float scale = 0.17677669529663687f;  // 32^-0.5
    float linv[4];
#pragma unroll
    for (int nt = 0; nt < 4; ++nt) {
        int i = nt * 16 + c;
        float s[16];
        float mx = -3.0e38f;
#pragma unroll
        for (int mt = 0; mt < 4; ++mt) {
            bf16x4 pmv = *(const bf16x4*)(pmS + i * PMP + mt * 16 + g * 4);
#pragma unroll
            for (int r = 0; r < 4; ++r) {
                float sv = sacc[mt][nt][r] * scale + (float)pmv[r];
                s[mt * 4 + r] = sv;
                mx = fmaxf(mx, sv);
            }
        }
        mx = fmaxf(mx, __shfl_xor(mx, 16));
        mx = fmaxf(mx, __shfl_xor(mx, 32));
        float sum = 0.f;
#pragma unroll
        for (int k2 = 0; k2 < 16; ++k2) {
            float p = __expf(s[k2] - mx);
            s[k2] = p;
            sum += p;
        }
        sum += __shfl_xor(sum, 16);
        sum += __shfl_xor(sum, 32);
        linv[nt] = 1.0f / sum;
        // store P row-major [i][t] (C/D 4 rows are 4 consecutive t -> b64)
#pragma unroll
        for (int mt = 0; mt < 4; ++mt) {
            bf16x4 p4 = {(bf16_t)s[mt * 4 + 0], (bf16_t)s[mt * 4 + 1],
                         (bf16_t)s[mt * 4 + 2], (bf16_t)s[mt * 4 + 3]};
            *(bf16x4*)(Ph + i * PP + mt * 16 + g * 4) = p4;
        }
    }
    __syncthreads();  // all q/k/pm reads done -> qS region reusable as attn_out

    // O^T = V^T (A) * P^T (B):  O^T[d][i] = sum_t v[t][d] P[i][t]
    f32x4 oacc[2][4];
#pragma unroll
    for (int md = 0; md < 2; ++md)
#pragma unroll
        for (int nt = 0; nt < 4; ++nt) oacc[md][nt] = (f32x4){0.f, 0.f, 0.f, 0.f};

#pragma unroll
    for (int ks = 0; ks < 2; ++ks) {
        bf16x8 Av[2];
#pragma unroll
        for (int md = 0; md < 2; ++md)
            Av[md] = *(const bf16x8*)(vh + (md * 16 + c) * VP + ks * 32 + g * 8);
#pragma unroll
        for (int nt = 0; nt < 4; ++nt) {
            bf16x8 Bp = *(const bf16x8*)(Ph + (nt * 16 + c) * PP + ks * 32 + g * 8);
#pragma unroll
            for (int md = 0; md < 2; ++md)
                oacc[md][nt] = MFMA16(Av[md], Bp, oacc[md][nt]);
        }
    }

    // store O / l into attn_out[tok][h*32+d]  (C/D rows = 4 consecutive d -> b64)
#pragma unroll
    for (int md = 0; md < 2; ++md)
#pragma unroll
        for (int nt = 0; nt < 4; ++nt) {
            f32x4 o = oacc[md][nt];
            float li = linv[nt];
            bf16x4 v4 = {(bf16_t)(o[0] * li), (bf16_t)(o[1] * li),
                         (bf16_t)(o[2] * li), (bf16_t)(o[3] * li)};
            *(bf16x4*)(aoS + (nt * 16 + c) * AOP + wid * 32 + md * 16 + g * 4) = v4;
        }
    __syncthreads();  // attn_out complete

    // =========== Phase C: out = attn_out @ w_proj + bias ===========
    // M = tok (4 mtiles), N = ch2 (12 ntiles, wave owns 2), K = 192 (6 ksteps)
    f32x4 pacc[4][2];
#pragma unroll
    for (int mt = 0; mt < 4; ++mt)
#pragma unroll
        for (int nl = 0; nl < 2; ++nl) pacc[mt][nl] = (f32x4){0.f, 0.f, 0.f, 0.f};

#pragma unroll
    for (int ks = 0; ks < 6; ++ks) {
        bf16x8 Bw[2];
#pragma unroll
        for (int nl = 0; nl < 2; ++nl)
            Bw[nl] = *(const bf16x8*)(w2B + (((size_t)ks * 12 + wid * 2 + nl) * 64 + lane) * 8);
#pragma unroll
        for (int mt = 0; mt < 4; ++mt) {
            bf16x8 Ao = *(const bf16x8*)(aoS + (mt * 16 + c) * AOP + ks * 32 + g * 8);
#pragma unroll
            for (int nl = 0; nl < 2; ++nl)
                pacc[mt][nl] = MFMA16(Ao, Bw[nl], pacc[mt][nl]);
        }
    }

    float bb0 = bias[(wid * 2 + 0) * 16 + c];
    float bb1 = bias[(wid * 2 + 1) * 16 + c];
    float* ob = out + (size_t)b * (49 * 192);
#pragma unroll
    for (int mt = 0; mt < 4; ++mt)
#pragma unroll
        for (int nl = 0; nl < 2; ++nl) {
            int ch2 = (wid * 2 + nl) * 16 + c;
            float bbv = nl ? bb1 : bb0;
            f32x4 a = pacc[mt][nl];
#pragma unroll
            for (int r = 0; r < 4; ++r) {
                int tok = mt * 16 + g * 4 + r;
                if (tok < 49) ob[(size_t)tok * 192 + ch2] = a[r] + bbv;
            }
        }
}

// ---------------------------------------------------------------------------
extern "C" void kernel_launch(void* const* d_in, const int* in_sizes, int n_in,
                              void* d_out, int out_size, void* d_ws, size_t ws_size,
                              hipStream_t stream) {
    const float* x     = (const float*)d_in[0];
    const float* mask  = (const float*)d_in[1];
    const float* wqkv  = (const float*)d_in[2];
    const float* wproj = (const float*)d_in[3];
    const float* bias  = (const float*)d_in[4];
    float* out = (float*)d_out;

    bf16_t* wA  = (bf16_t*)d_ws;          // 110592 bf16
    bf16_t* w2B = wA + 110592;            //  36864 bf16

    prep_weights<<<576, 256, 0, stream>>>(wqkv, wproj, wA, w2B);
    fused_window_attn<<<4096, 384, 0, stream>>>(x, mask, wA, w2B, bias, out);
}

// Round 2
// 421.053 us; speedup vs baseline: 1.2446x; 1.2446x over previous
//
#include <hip/hip_runtime.h>

using bf16_t = __bf16;
using bf16x4 = __bf16 __attribute__((ext_vector_type(4)));
using bf16x8 = __bf16 __attribute__((ext_vector_type(8)));
using f32x4  = float  __attribute__((ext_vector_type(4)));

#define MFMA16(a, b, c) __builtin_amdgcn_mfma_f32_16x16x32_bf16((a), (b), (c), 0, 0, 0)

// 8-byte-aligned bf16x8 load as two b64s
__device__ __forceinline__ bf16x8 ld_b8_2x(const bf16_t* p) {
    bf16x4 lo = *(const bf16x4*)p;
    bf16x4 hi = *(const bf16x4*)(p + 4);
    bf16x8 r;
    r[0] = lo[0]; r[1] = lo[1]; r[2] = lo[2]; r[3] = lo[3];
    r[4] = hi[0]; r[5] = hi[1]; r[6] = hi[2]; r[7] = hi[3];
    return r;
}

// ---------------------------------------------------------------------------
// Prep: swizzle weights into fragment order (bf16) in workspace.
//  wA  [mt(36)][ks(6)][lane(64)][8] : A-frag of w_qkv^T
//  w2B [ks(6)][nt(12)][lane(64)][8] : B-frag of w_proj
// ---------------------------------------------------------------------------
__global__ void prep_weights(const float* __restrict__ wqkv,
                             const float* __restrict__ wproj,
                             bf16_t* __restrict__ wA,
                             bf16_t* __restrict__ w2B) {
    int idx = blockIdx.x * 256 + threadIdx.x;
    const int N1 = 36 * 6 * 64 * 8;  // 110592
    if (idx < N1) {
        int j = idx & 7, L = (idx >> 3) & 63, q = idx >> 9;
        int ks = q % 6, mt = q / 6;
        int cc = ks * 32 + (L >> 4) * 8 + j;
        int ch = mt * 16 + (L & 15);
        wA[idx] = (bf16_t)wqkv[cc * 576 + ch];
    } else {
        int idx2 = idx - N1;
        if (idx2 < 6 * 12 * 64 * 8) {
            int j = idx2 & 7, L = (idx2 >> 3) & 63, q = idx2 >> 9;
            int nt = q % 12, ks = q / 12;
            int cc = ks * 32 + (L >> 4) * 8 + j;
            int ch = nt * 16 + (L & 15);
            w2B[idx2] = (bf16_t)wproj[cc * 192 + ch];
        }
    }
}

// ---------------------------------------------------------------------------
// Fused window attention: 4096 blocks x 1024 threads (16 waves), 1 window/blk
// LDS map (bytes):
//   [0,      30720)  qS  [6][64][40]       (aliased later by aoS [64][204])
//   [30720,  61440)  kS  [6][64][40]
//   [61440,  89088)  vS  [6][64][36] row-major
//   [89088,  98304)  pmS [64][72]
//   [98304, 147456)  pS  [6 heads][64 rows][128 B] XOR-chunk-swizzled
//                    (aliased in phase A by xS [64][204] bf16)
// ---------------------------------------------------------------------------
__global__ __launch_bounds__(1024, 4) void fused_window_attn(
    const float* __restrict__ x,     // [4096][49][192]
    const float* __restrict__ mask,  // [64][1][49][49]
    const bf16_t* __restrict__ wA,
    const bf16_t* __restrict__ w2B,
    const float* __restrict__ bias,  // [192]
    float* __restrict__ out)         // [4096][49][192]
{
    constexpr int QP  = 40;   // q/k pitch (elems)
    constexpr int VP  = 36;   // v pitch (row-major [tok][d])
    constexpr int PMP = 72;   // premask pitch
    constexpr int AOP = 204;  // attn_out / staged-x pitch

    __shared__ __align__(16) char smem[147456];
    bf16_t* qS  = (bf16_t*)smem;          // elem offsets
    bf16_t* kS  = qS + 15360;
    bf16_t* vS  = qS + 30720;
    bf16_t* pmS = qS + 44544;
    char*   pB  = smem + 98304;           // swizzled P (byte-addressed)
    bf16_t* xS  = (bf16_t*)(smem + 98304);
    bf16_t* aoS = (bf16_t*)smem;

    const int b    = blockIdx.x;
    const int tid  = threadIdx.x;
    const int wid  = tid >> 6;   // 0..15
    const int lane = tid & 63;
    const int g    = lane >> 4;
    const int c    = lane & 15;

    // ---- stage x (fp32->bf16, zero-pad tok>=49) into xS [64][204] ----
    const float* xb = x + (size_t)b * (49 * 192);
    for (int ch4 = tid; ch4 < 64 * 48; ch4 += 1024) {
        int tok = ch4 / 48, c4 = ch4 % 48;
        f32x4 v = (f32x4){0.f, 0.f, 0.f, 0.f};
        if (tok < 49) v = *(const f32x4*)(xb + tok * 192 + c4 * 4);
        bf16x4 o = {(bf16_t)v[0], (bf16_t)v[1], (bf16_t)v[2], (bf16_t)v[3]};
        *(bf16x4*)(xS + tok * AOP + c4 * 4) = o;
    }
    // ---- stage premask [64][72] ----
    const float* mw = mask + (size_t)(b & 63) * (49 * 49);
    for (int idx = tid; idx < 64 * 64; idx += 1024) {
        int i = idx >> 6, t = idx & 63;
        float v;
        if (t < 49) v = (i < 49) ? mw[i * 49 + t] : 0.0f;
        else        v = -1e30f;
        pmS[i * PMP + t] = (bf16_t)v;
    }
    __syncthreads();  // B0: xS, pmS ready

    // =========== Phase A: qkv^T = w_qkv^T (A) * x^T (B) ===========
    // 36 mtiles of ch3; waves 0..3 take 3, waves 4..15 take 2.
    const int nmt = (wid < 4) ? 3 : 2;
    const int mt0 = (wid < 4) ? wid * 3 : 12 + (wid - 4) * 2;

    f32x4 acc[3][4];
#pragma unroll
    for (int m = 0; m < 3; ++m)
#pragma unroll
        for (int n = 0; n < 4; ++n) acc[m][n] = (f32x4){0.f, 0.f, 0.f, 0.f};

#pragma unroll
    for (int ks = 0; ks < 6; ++ks) {
        bf16x8 Bf[4];
#pragma unroll
        for (int nt = 0; nt < 4; ++nt)
            Bf[nt] = ld_b8_2x(xS + (nt * 16 + c) * AOP + ks * 32 + g * 8);
#pragma unroll
        for (int m = 0; m < 3; ++m) {
            if (m < nmt) {
                int mt = mt0 + m;
                bf16x8 Af = *(const bf16x8*)(wA + (((size_t)mt * 6 + ks) * 64 + lane) * 8);
#pragma unroll
                for (int nt = 0; nt < 4; ++nt)
                    acc[m][nt] = MFMA16(Af, Bf[nt], acc[m][nt]);
            }
        }
    }

    // route: q,k -> [h][tok][40] row-major; v -> [h][tok][36] row-major
#pragma unroll
    for (int m = 0; m < 3; ++m) {
        if (m < nmt) {
            int mt  = mt0 + m;
            int typ = mt / 12;                       // wave-uniform
            int rel = (mt - typ * 12) * 16 + g * 4;  // 0..191 in q/k/v
            int hh  = rel >> 5;
            int dd0 = rel & 31;
#pragma unroll
            for (int nt = 0; nt < 4; ++nt) {
                int tok = nt * 16 + c;
                f32x4 a = acc[m][nt];
                bf16x4 v4 = {(bf16_t)a[0], (bf16_t)a[1], (bf16_t)a[2], (bf16_t)a[3]};
                if (typ == 0)      *(bf16x4*)(qS + hh * (64 * QP) + tok * QP + dd0) = v4;
                else if (typ == 1) *(bf16x4*)(kS + hh * (64 * QP) + tok * QP + dd0) = v4;
                else               *(bf16x4*)(vS + hh * (64 * VP) + tok * VP + dd0) = v4;
            }
        }
    }
    __syncthreads();  // B1: qkv + pm ready; xS dead

    // =========== Phase B: attention. 12 wave-tasks = head(6) x i-half(2) ====
    const int h = wid >> 1;
    const int u = wid & 1;
    f32x4 oacc[2][2];
#pragma unroll
    for (int a0 = 0; a0 < 2; ++a0)
#pragma unroll
        for (int a1 = 0; a1 < 2; ++a1) oacc[a0][a1] = (f32x4){0.f, 0.f, 0.f, 0.f};

    if (wid < 12) {
        const bf16_t* qh = qS + h * (64 * QP);
        const bf16_t* kh = kS + h * (64 * QP);
        const bf16_t* vh = vS + h * (64 * VP);
        char*         Ph = pB + h * 8192;  // 64 rows x 128 B, swizzled

        // S^T[t][i] = sum_d k[t][d] q[i][d]; A=k (4 mt), B=q (2 nt)
        bf16x8 Ak[4], Bq[2];
#pragma unroll
        for (int mt = 0; mt < 4; ++mt)
            Ak[mt] = *(const bf16x8*)(kh + (mt * 16 + c) * QP + g * 8);
#pragma unroll
        for (int nl = 0; nl < 2; ++nl)
            Bq[nl] = *(const bf16x8*)(qh + ((2 * u + nl) * 16 + c) * QP + g * 8);

        f32x4 sacc[4][2];
#pragma unroll
        for (int mt = 0; mt < 4; ++mt)
#pragma unroll
            for (int nl = 0; nl < 2; ++nl) sacc[mt][nl] = (f32x4){0.f, 0.f, 0.f, 0.f};
#pragma unroll
        for (int mt = 0; mt < 4; ++mt)
#pragma unroll
            for (int nl = 0; nl < 2; ++nl)
                sacc[mt][nl] = MFMA16(Ak[mt], Bq[nl], sacc[mt][nl]);

        // softmax over t for i-rows of this half; fold 1/l into P
        const float scale = 0.17677669529663687f;  // 32^-0.5
#pragma unroll
        for (int nl = 0; nl < 2; ++nl) {
            int i = (2 * u + nl) * 16 + c;
            float s[16];
            float mx = -3.0e38f;
#pragma unroll
            for (int mt = 0; mt < 4; ++mt) {
                bf16x4 pmv = *(const bf16x4*)(pmS + i * PMP + mt * 16 + g * 4);
#pragma unroll
                for (int r = 0; r < 4; ++r) {
                    float sv = sacc[mt][nl][r] * scale + (float)pmv[r];
                    s[mt * 4 + r] = sv;
                    mx = fmaxf(mx, sv);
                }
            }
            mx = fmaxf(mx, __shfl_xor(mx, 16));
            mx = fmaxf(mx, __shfl_xor(mx, 32));
            float sum = 0.f;
#pragma unroll
            for (int k2 = 0; k2 < 16; ++k2) {
                float p = __expf(s[k2] - mx);
                s[k2] = p;
                sum += p;
            }
            sum += __shfl_xor(sum, 16);
            sum += __shfl_xor(sum, 32);
            float linv = 1.0f / sum;
            // store normalized P, XOR-chunk swizzle: row i, chunk tc^(i&7)
#pragma unroll
            for (int mt = 0; mt < 4; ++mt) {
                int tc = 2 * mt + (g >> 1);
                bf16x4 p4 = {(bf16_t)(s[mt * 4 + 0] * linv), (bf16_t)(s[mt * 4 + 1] * linv),
                             (bf16_t)(s[mt * 4 + 2] * linv), (bf16_t)(s[mt * 4 + 3] * linv)};
                *(bf16x4*)(Ph + i * 128 + ((tc ^ (i & 7)) << 4) + ((g & 1) << 3)) = p4;
            }
        }

        // O[i][d] = sum_t P[i][t] v[t][d];  A=P (swizzled b128), B=v (scalar)
#pragma unroll
        for (int ks = 0; ks < 2; ++ks) {
            bf16x8 Bv[2];
#pragma unroll
            for (int nd = 0; nd < 2; ++nd) {
                bf16x8 t;
#pragma unroll
                for (int j = 0; j < 8; ++j)
                    t[j] = vh[(ks * 32 + g * 8 + j) * VP + nd * 16 + c];
                Bv[nd] = t;
            }
#pragma unroll
            for (int nl = 0; nl < 2; ++nl) {
                int i = (2 * u + nl) * 16 + c;
                bf16x8 Ap = *(const bf16x8*)(Ph + i * 128 + (((4 * ks + g) ^ (i & 7)) << 4));
#pragma unroll
                for (int nd = 0; nd < 2; ++nd)
                    oacc[nl][nd] = MFMA16(Ap, Bv[nd], oacc[nl][nd]);
            }
        }
    }
    __syncthreads();  // B2: all q/k/v/pm reads done -> qS reusable as aoS

    if (wid < 12) {
#pragma unroll
        for (int nl = 0; nl < 2; ++nl)
#pragma unroll
            for (int nd = 0; nd < 2; ++nd) {
                f32x4 o = oacc[nl][nd];
#pragma unroll
                for (int r = 0; r < 4; ++r) {
                    int i = (2 * u + nl) * 16 + 4 * g + r;
                    aoS[i * AOP + h * 32 + nd * 16 + c] = (bf16_t)o[r];
                }
            }
    }
    __syncthreads();  // B3: attn_out ready

    // =========== Phase C: out = attn_out @ w_proj + bias ===========
    // 48 tiles = mt(4) x ntile(12); wave -> mt = wid&3, ntiles g3*3..g3*3+2
    const int mt = wid & 3;
    const int g3 = wid >> 2;
    f32x4 pacc[3];
#pragma unroll
    for (int j = 0; j < 3; ++j) pacc[j] = (f32x4){0.f, 0.f, 0.f, 0.f};

#pragma unroll
    for (int ks = 0; ks < 6; ++ks) {
        bf16x8 Ao = ld_b8_2x(aoS + (mt * 16 + c) * AOP + ks * 32 + g * 8);
#pragma unroll
        for (int j = 0; j < 3; ++j) {
            bf16x8 Bw = *(const bf16x8*)(w2B + (((size_t)ks * 12 + g3 * 3 + j) * 64 + lane) * 8);
            pacc[j] = MFMA16(Ao, Bw, pacc[j]);
        }
    }

    float* ob = out + (size_t)b * (49 * 192);
#pragma unroll
    for (int j = 0; j < 3; ++j) {
        int ch2 = (g3 * 3 + j) * 16 + c;
        float bbv = bias[ch2];
        f32x4 a = pacc[j];
#pragma unroll
        for (int r = 0; r < 4; ++r) {
            int tok = mt * 16 + 4 * g + r;
            if (tok < 49) ob[(size_t)tok * 192 + ch2] = a[r] + bbv;
        }
    }
}

// ---------------------------------------------------------------------------
extern "C" void kernel_launch(void* const* d_in, const int* in_sizes, int n_in,
                              void* d_out, int out_size, void* d_ws, size_t ws_size,
                              hipStream_t stream) {
    const float* x     = (const float*)d_in[0];
    const float* mask  = (const float*)d_in[1];
    const float* wqkv  = (const float*)d_in[2];
    const float* wproj = (const float*)d_in[3];
    const float* bias  = (const float*)d_in[4];
    float* out = (float*)d_out;

    bf16_t* wA  = (bf16_t*)d_ws;   // 110592 bf16
    bf16_t* w2B = wA + 110592;     //  36864 bf16

    prep_weights<<<576, 256, 0, stream>>>(wqkv, wproj, wA, w2B);
    fused_window_attn<<<4096, 1024, 0, stream>>>(x, mask, wA, w2B, bias, out);
}